// Round 1
// 579.880 us; speedup vs baseline: 1.0523x; 1.0523x over previous
//
#include <hip/hip_runtime.h>
#include <hip/hip_fp16.h>

#define NN 10000
#define FF 32
#define PG 4      // pairs per group
#define NGRP 24   // 96 pairs / PG

__device__ __forceinline__ unsigned short f2h(float f){
  union { unsigned short s; _Float16 h; } c; c.h = (_Float16)f; return c.s;
}

// ---- CSR build -------------------------------------------------------------
__global__ void k_count(const int* __restrict__ dst, int* __restrict__ cnt, int E){
  int e = blockIdx.x * 256 + threadIdx.x;
  if (e < E) atomicAdd(&cnt[dst[e]], 1);
}

// exclusive scan of PADDED counts (pad to multiple of 4); dinv from real count.
// Also computes W12 = W1@W2 and bb = b1@W2 (fused to save a dispatch).
__global__ __launch_bounds__(1024) void k_scan(const int* __restrict__ cnt,
                                               int* __restrict__ off,
                                               float* __restrict__ dinv,
                                               const float* __restrict__ W1,
                                               const float* __restrict__ W2,
                                               const float* __restrict__ b1,
                                               float* __restrict__ W12,
                                               float* __restrict__ bb){
  __shared__ int wsum[16];
  __shared__ int carry;
  int tid = threadIdx.x, lane = tid & 63, wv = tid >> 6;
  if (tid == 0) carry = 0;
  __syncthreads();
  for (int base = 0; base < NN; base += 1024){
    int i = base + tid;
    int c = (i < NN) ? cnt[i] : 0;
    int v = (c + 3) & ~3;                      // padded degree
    int s = v;
    #pragma unroll
    for (int o = 1; o < 64; o <<= 1){
      int t = __shfl_up(s, o, 64);
      if (lane >= o) s += t;
    }
    if (lane == 63) wsum[wv] = s;
    __syncthreads();
    if (tid == 0){
      int a = carry;
      #pragma unroll
      for (int k = 0; k < 16; ++k){ int t = wsum[k]; wsum[k] = a; a += t; }
      carry = a;
    }
    __syncthreads();
    if (i < NN){
      off[i]  = wsum[wv] + s - v;              // exclusive padded offset
      dinv[i] = rsqrtf((float)(c + 1));        // real degree + self loop
    }
    __syncthreads();
  }
  if (tid == 0) off[NN] = carry;
  // fused W12 / bb
  for (int idx = tid; idx < 33 * 32; idx += 1024){
    int k = idx >> 5, j = idx & 31;
    float s = 0.f;
    for (int m = 0; m < 64; ++m) s += W1[k * 64 + m] * W2[m * 32 + j];
    W12[idx] = s;
  }
  if (tid < 32){
    int j = tid;
    float s = 0.f;
    for (int m = 0; m < 64; ++m) s += b1[m] * W2[m * 32 + j];
    bb[j] = s;
  }
}

// csr entry: {row byte offset (src*256), fp32 weight dinv[src]}
// pad holes (memset 0) read row 0 with weight 0.0 -> harmless.
__global__ void k_scatter(const int* __restrict__ ei, const int* __restrict__ off,
                          int* __restrict__ cur, const float* __restrict__ dinv,
                          int2* __restrict__ csr, int E){
  int e = blockIdx.x * 256 + threadIdx.x;
  if (e >= E) return;
  int s = ei[e], d = ei[E + e];
  int pos = off[d] + atomicAdd(&cur[d], 1);
  csr[pos] = make_int2(s << 8, __float_as_int(dinv[s]));
}

// ---- s[n] = rowsum(A) ------------------------------------------------------
__global__ void k_srow(const int* __restrict__ off, const int2* __restrict__ csr,
                       const float* __restrict__ dinv, float* __restrict__ srow){
  int n = blockIdx.x * 256 + threadIdx.x;
  if (n >= NN) return;
  float a = dinv[n];
  int e0 = off[n], e1 = off[n + 1];
  for (int j = e0; j < e1; ++j) a += __int_as_float(csr[j].y);  // pads add 0
  srow[n] = dinv[n] * a;
}

// ---- GEMM1 v2: one thread = one (pg, node), all 32 features ----------------
// Each lane loads its OWN 128-B x row (8 KB unique bytes in flight per wave,
// vs 512 B in the old q-lane mapping) -> HBM latency fully hidden by the
// 1056-FMA body. W12 accessed only at wave-uniform constant offsets -> s_load.
// Output layout identical to before: hw[grp][n][p*16+q] packs features
// (2q, 2q+1) as two fp16 in one dword; thread writes one full 64-B line.
__global__ __launch_bounds__(256) void k_gemm1(const float* __restrict__ x,
    const float* __restrict__ mask, const float* __restrict__ W12,
    unsigned* __restrict__ hw){
  const int pg = blockIdx.y;                  // 0..95 (b*24+h)
  const int n  = blockIdx.x * 256 + threadIdx.x;
  const int grp = pg >> 2, p = pg & 3;
  const float mv = mask[pg];
  float acc[32];
  #pragma unroll
  for (int f = 0; f < 32; ++f) acc[f] = mv * W12[32 * 32 + f];  // mask row
  if (n >= NN) return;
  const float4* xp = (const float4*)(x + (size_t)pg * (NN * FF) + (size_t)n * FF);
  float xv[32];
  #pragma unroll
  for (int i = 0; i < 8; ++i){
    float4 v = xp[i];
    xv[4*i]   = v.x; xv[4*i+1] = v.y;
    xv[4*i+2] = v.z; xv[4*i+3] = v.w;
  }
  #pragma unroll
  for (int k = 0; k < 32; ++k){
    const float xk = xv[k];
    #pragma unroll
    for (int f = 0; f < 32; ++f) acc[f] += xk * W12[k * 32 + f];
  }
  unsigned* hwg = hw + (size_t)grp * (NN * 64) + ((size_t)n << 6) + (p << 4);
  #pragma unroll
  for (int j = 0; j < 4; ++j){
    uint4 u;
    u.x = (unsigned)f2h(acc[8*j+0]) | ((unsigned)f2h(acc[8*j+1]) << 16);
    u.y = (unsigned)f2h(acc[8*j+2]) | ((unsigned)f2h(acc[8*j+3]) << 16);
    u.z = (unsigned)f2h(acc[8*j+4]) | ((unsigned)f2h(acc[8*j+5]) << 16);
    u.w = (unsigned)f2h(acc[8*j+6]) | ((unsigned)f2h(acc[8*j+7]) << 16);
    ((uint4*)hwg)[j] = u;
  }
}

// ---- block->group mapping: pin each group to one XCD (blockIdx%8) ----------
__device__ __forceinline__ void map_block(int bx, int& grp, int& chunk){
  int r  = bx / 5000;       // 0..2
  int w8 = bx % 5000;
  grp   = r * 8 + (w8 & 7);
  chunk = w8 >> 3;          // 0..624
}

// 2-deep pipelined edge accumulation: csr q+2 loading, gathers q+1 in flight,
// fma on quad q. Clamped indices instead of branches (dup loads are L1-hot).
__device__ __forceinline__ void agg_edges(int e0, int e1,
    const int2* __restrict__ csr, const char* __restrict__ Vb, int loff,
    float& ax, float& ay){
  int nq = (e1 - e0) >> 2;
  if (nq <= 0) return;
  const int4* c4 = (const int4*)(csr + e0);
  int qlast = nq - 1;
  int4 ca0 = c4[0], cb0 = c4[1];
  int i1 = (1 <= qlast) ? 1 : qlast;
  int4 ca1 = c4[2 * i1], cb1 = c4[2 * i1 + 1];
  unsigned r0 = *(const unsigned*)(Vb + ca0.x + loff);
  unsigned r1 = *(const unsigned*)(Vb + ca0.z + loff);
  unsigned r2 = *(const unsigned*)(Vb + cb0.x + loff);
  unsigned r3 = *(const unsigned*)(Vb + cb0.z + loff);
  for (int q = 0; q < nq; ++q){
    unsigned s0 = *(const unsigned*)(Vb + ca1.x + loff);
    unsigned s1 = *(const unsigned*)(Vb + ca1.z + loff);
    unsigned s2 = *(const unsigned*)(Vb + cb1.x + loff);
    unsigned s3 = *(const unsigned*)(Vb + cb1.z + loff);
    int i2 = (q + 2 <= qlast) ? q + 2 : qlast;
    int4 na = c4[2 * i2], nb = c4[2 * i2 + 1];
    float w0 = __int_as_float(ca0.y), w1 = __int_as_float(ca0.w);
    float w2 = __int_as_float(cb0.y), w3 = __int_as_float(cb0.w);
    union { unsigned u; _Float16 h[2]; } u0, u1, u2, u3;
    u0.u = r0; u1.u = r1; u2.u = r2; u3.u = r3;
    ax += w0*(float)u0.h[0] + w1*(float)u1.h[0] + w2*(float)u2.h[0] + w3*(float)u3.h[0];
    ay += w0*(float)u0.h[1] + w1*(float)u1.h[1] + w2*(float)u2.h[1] + w3*(float)u3.h[1];
    ca0 = ca1; cb0 = cb1; ca1 = na; cb1 = nb;
    r0 = s0; r1 = s1; r2 = s2; r3 = s3;
  }
}

// ---- agg layer 1: t1 = A*hw (fp16 rows, fp32 accum) ------------------------
__global__ __launch_bounds__(256) void k_agg1(const int* __restrict__ off,
    const int2* __restrict__ csr, const float* __restrict__ dinv,
    const unsigned int* __restrict__ V, unsigned int* __restrict__ T){
  int grp, chunk; map_block(blockIdx.x, grp, chunk);
  int tid = threadIdx.x;
  int l = tid & 63;
  int wv = __builtin_amdgcn_readfirstlane(tid) >> 6;   // wave-uniform
  const char* Vb = (const char*)(V + (size_t)grp * (NN * 64));
  unsigned int* Tg = T + (size_t)grp * (NN * 64);
  int loff = l * 4;
  for (int it = 0; it < 4; ++it){
    int n = chunk * 16 + wv * 4 + it;
    float din = dinv[n];
    int e0 = off[n], e1 = off[n + 1];
    unsigned sv = *(const unsigned*)(Vb + (n << 8) + loff);
    union { unsigned u; _Float16 h[2]; } cv; cv.u = sv;
    float ax = din * (float)cv.h[0];
    float ay = din * (float)cv.h[1];
    agg_edges(e0, e1, csr, Vb, loff, ax, ay);
    Tg[((size_t)n << 6) + l] =
        (unsigned)f2h(din * ax) | ((unsigned)f2h(din * ay) << 16);
  }
}

// ---- agg layer 2 + epilogue: out = tanh(A*t1 + srow*bb + b2) fp32 ----------
__global__ __launch_bounds__(256) void k_agg2(const int* __restrict__ off,
    const int2* __restrict__ csr, const float* __restrict__ dinv,
    const float* __restrict__ srow, const float* __restrict__ bb,
    const float* __restrict__ b2, const unsigned int* __restrict__ V,
    float* __restrict__ out){
  int grp, chunk; map_block(blockIdx.x, grp, chunk);
  int tid = threadIdx.x;
  int l = tid & 63;
  int wv = __builtin_amdgcn_readfirstlane(tid) >> 6;
  int p = l >> 4, fi = l & 15;
  const char* Vb = (const char*)(V + (size_t)grp * (NN * 64));
  int pg = grp * PG + p;
  float2 bbq = ((const float2*)bb)[fi];
  float2 b2q = ((const float2*)b2)[fi];
  float* outp = out + (size_t)pg * (NN * FF);
  int loff = l * 4;
  for (int it = 0; it < 4; ++it){
    int n = chunk * 16 + wv * 4 + it;
    float din = dinv[n];
    int e0 = off[n], e1 = off[n + 1];
    unsigned sv = *(const unsigned*)(Vb + (n << 8) + loff);
    union { unsigned u; _Float16 h[2]; } cv; cv.u = sv;
    float ax = din * (float)cv.h[0];
    float ay = din * (float)cv.h[1];
    agg_edges(e0, e1, csr, Vb, loff, ax, ay);
    float sr = srow[n];
    float2 o;
    o.x = tanhf(din * ax + sr * bbq.x + b2q.x);
    o.y = tanhf(din * ay + sr * bbq.y + b2q.y);
    ((float2*)(outp + (size_t)n * FF))[fi] = o;
  }
}

extern "C" void kernel_launch(void* const* d_in, const int* in_sizes, int n_in,
                              void* d_out, int out_size, void* d_ws, size_t ws_size,
                              hipStream_t stream){
  const float* x    = (const float*)d_in[0];
  const float* mask = (const float*)d_in[1];
  const int*   ei   = (const int*)d_in[2];
  const float* W1   = (const float*)d_in[3];
  const float* b1   = (const float*)d_in[4];
  const float* W2   = (const float*)d_in[5];
  const float* b2   = (const float*)d_in[6];
  float* out = (float*)d_out;
  const int E = in_sizes[2] / 2;   // 320000
  const int CSRCAP = E + 3 * NN + 64;  // padded-to-4 worst case + overread slack

  char* wsp = (char*)d_ws;
  auto alloc = [&](size_t bytes) -> char* {
    char* p = wsp; wsp += (bytes + 255) & ~(size_t)255; return p;
  };
  int*   cnt  = (int*)  alloc((size_t)NN * 4);
  int*   off  = (int*)  alloc((size_t)(NN + 1) * 4);
  int*   cur  = (int*)  alloc((size_t)NN * 4);
  float* dinv = (float*)alloc((size_t)NN * 4);
  float* srow = (float*)alloc((size_t)NN * 4);
  float* W12  = (float*)alloc(33 * 32 * 4);
  float* bbv  = (float*)alloc(32 * 4);
  int2*  csr  = (int2*) alloc((size_t)CSRCAP * 8);
  const size_t per_group = (size_t)NN * 64 * 4;    // [n][4p][32f] fp16 = 2.56MB
  unsigned int* hw = (unsigned int*)alloc((size_t)NGRP * per_group);
  unsigned int* t1 = (unsigned int*)alloc((size_t)NGRP * per_group);

  hipMemsetAsync(cnt, 0, (size_t)NN * 4, stream);
  hipMemsetAsync(cur, 0, (size_t)NN * 4, stream);
  hipMemsetAsync(csr, 0, (size_t)CSRCAP * 8, stream);   // pad entries: row 0, w=0
  k_count  <<<(E + 255) / 256, 256, 0, stream>>>(ei + E, cnt, E);
  k_scan   <<<1, 1024, 0, stream>>>(cnt, off, dinv, W1, W2, b1, W12, bbv);
  k_scatter<<<(E + 255) / 256, 256, 0, stream>>>(ei, off, cur, dinv, csr, E);
  k_srow   <<<(NN + 255) / 256, 256, 0, stream>>>(off, csr, dinv, srow);

  k_gemm1<<<dim3(40, 96), 256, 0, stream>>>(x, mask, W12, hw);
  k_agg1 <<<15000, 256, 0, stream>>>(off, csr, dinv, hw, t1);
  k_agg2 <<<15000, 256, 0, stream>>>(off, csr, dinv, srow, bbv, b2, t1, out);
}

// Round 2
// 556.973 us; speedup vs baseline: 1.0956x; 1.0411x over previous
//
#include <hip/hip_runtime.h>
#include <hip/hip_fp16.h>

#define NN 10000
#define FF 32
#define PG 4      // pairs per group
#define NGRP 24   // 96 pairs / PG

__device__ __forceinline__ unsigned short f2h(float f){
  union { unsigned short s; _Float16 h; } c; c.h = (_Float16)f; return c.s;
}

// acc.x += w * lo_f16(h); acc.y += w * hi_f16(h)  -- one VOP3P instr each.
// op_sel_hi[1]=1 marks S1 as f16; op_sel[1] picks the half. S0/S2 stay f32.
__device__ __forceinline__ void fmix2(float& ax, float& ay, float w, unsigned h){
  asm("v_fma_mix_f32 %0, %2, %3, %0 op_sel_hi:[0,1,0]\n\t"
      "v_fma_mix_f32 %1, %2, %3, %1 op_sel:[0,1,0] op_sel_hi:[0,1,0]"
      : "+v"(ax), "+v"(ay) : "v"(w), "v"(h));
}

// ---- CSR build -------------------------------------------------------------
__global__ void k_count(const int* __restrict__ dst, int* __restrict__ cnt, int E){
  int e = blockIdx.x * 256 + threadIdx.x;
  if (e < E) atomicAdd(&cnt[dst[e]], 1);
}

// exclusive scan of PADDED counts (pad to multiple of 4); dinv from real count.
// Also computes W12 = W1@W2 and bb = b1@W2 (fused to save a dispatch).
__global__ __launch_bounds__(1024) void k_scan(const int* __restrict__ cnt,
                                               int* __restrict__ off,
                                               float* __restrict__ dinv,
                                               const float* __restrict__ W1,
                                               const float* __restrict__ W2,
                                               const float* __restrict__ b1,
                                               float* __restrict__ W12,
                                               float* __restrict__ bb){
  __shared__ int wsum[16];
  __shared__ int carry;
  int tid = threadIdx.x, lane = tid & 63, wv = tid >> 6;
  if (tid == 0) carry = 0;
  __syncthreads();
  for (int base = 0; base < NN; base += 1024){
    int i = base + tid;
    int c = (i < NN) ? cnt[i] : 0;
    int v = (c + 3) & ~3;                      // padded degree
    int s = v;
    #pragma unroll
    for (int o = 1; o < 64; o <<= 1){
      int t = __shfl_up(s, o, 64);
      if (lane >= o) s += t;
    }
    if (lane == 63) wsum[wv] = s;
    __syncthreads();
    if (tid == 0){
      int a = carry;
      #pragma unroll
      for (int k = 0; k < 16; ++k){ int t = wsum[k]; wsum[k] = a; a += t; }
      carry = a;
    }
    __syncthreads();
    if (i < NN){
      off[i]  = wsum[wv] + s - v;              // exclusive padded offset
      dinv[i] = rsqrtf((float)(c + 1));        // real degree + self loop
    }
    __syncthreads();
  }
  if (tid == 0) off[NN] = carry;
  // fused W12 / bb
  for (int idx = tid; idx < 33 * 32; idx += 1024){
    int k = idx >> 5, j = idx & 31;
    float s = 0.f;
    for (int m = 0; m < 64; ++m) s += W1[k * 64 + m] * W2[m * 32 + j];
    W12[idx] = s;
  }
  if (tid < 32){
    int j = tid;
    float s = 0.f;
    for (int m = 0; m < 64; ++m) s += b1[m] * W2[m * 32 + j];
    bb[j] = s;
  }
}

// csr entry: {row byte offset (src*256), fp32 weight dinv[src]}
// pad holes (memset 0) read row 0 with weight 0.0 -> harmless.
__global__ void k_scatter(const int* __restrict__ ei, const int* __restrict__ off,
                          int* __restrict__ cur, const float* __restrict__ dinv,
                          int2* __restrict__ csr, int E){
  int e = blockIdx.x * 256 + threadIdx.x;
  if (e >= E) return;
  int s = ei[e], d = ei[E + e];
  int pos = off[d] + atomicAdd(&cur[d], 1);
  csr[pos] = make_int2(s << 8, __float_as_int(dinv[s]));
}

// ---- s[n] = rowsum(A) ------------------------------------------------------
__global__ void k_srow(const int* __restrict__ off, const int2* __restrict__ csr,
                       const float* __restrict__ dinv, float* __restrict__ srow){
  int n = blockIdx.x * 256 + threadIdx.x;
  if (n >= NN) return;
  float a = dinv[n];
  int e0 = off[n], e1 = off[n + 1];
  for (int j = e0; j < e1; ++j) a += __int_as_float(csr[j].y);  // pads add 0
  srow[n] = dinv[n] * a;
}

// ---- GEMM1 v2: one thread = one (pg, node), all 32 features ----------------
__global__ __launch_bounds__(256) void k_gemm1(const float* __restrict__ x,
    const float* __restrict__ mask, const float* __restrict__ W12,
    unsigned* __restrict__ hw){
  const int pg = blockIdx.y;                  // 0..95 (b*24+h)
  const int n  = blockIdx.x * 256 + threadIdx.x;
  const int grp = pg >> 2, p = pg & 3;
  const float mv = mask[pg];
  float acc[32];
  #pragma unroll
  for (int f = 0; f < 32; ++f) acc[f] = mv * W12[32 * 32 + f];  // mask row
  if (n >= NN) return;
  const float4* xp = (const float4*)(x + (size_t)pg * (NN * FF) + (size_t)n * FF);
  float xv[32];
  #pragma unroll
  for (int i = 0; i < 8; ++i){
    float4 v = xp[i];
    xv[4*i]   = v.x; xv[4*i+1] = v.y;
    xv[4*i+2] = v.z; xv[4*i+3] = v.w;
  }
  #pragma unroll
  for (int k = 0; k < 32; ++k){
    const float xk = xv[k];
    #pragma unroll
    for (int f = 0; f < 32; ++f) acc[f] += xk * W12[k * 32 + f];
  }
  unsigned* hwg = hw + (size_t)grp * (NN * 64) + ((size_t)n << 6) + (p << 4);
  #pragma unroll
  for (int j = 0; j < 4; ++j){
    uint4 u;
    u.x = (unsigned)f2h(acc[8*j+0]) | ((unsigned)f2h(acc[8*j+1]) << 16);
    u.y = (unsigned)f2h(acc[8*j+2]) | ((unsigned)f2h(acc[8*j+3]) << 16);
    u.z = (unsigned)f2h(acc[8*j+4]) | ((unsigned)f2h(acc[8*j+5]) << 16);
    u.w = (unsigned)f2h(acc[8*j+6]) | ((unsigned)f2h(acc[8*j+7]) << 16);
    ((uint4*)hwg)[j] = u;
  }
}

// ---- block->group mapping: pin each group to one XCD (blockIdx%8) ----------
__device__ __forceinline__ void map_block(int bx, int& grp, int& chunk){
  int r  = bx / 5000;       // 0..2
  int w8 = bx % 5000;
  grp   = r * 8 + (w8 & 7);
  chunk = w8 >> 3;          // 0..624
}

// 2-deep pipelined edge accumulation: csr q+2 loading, gathers q+1 in flight,
// fma_mix on quad q. Gathers use 32-bit voffset (ca.x + loff) against the
// wave-uniform Vb base -> saddr-form global_load, 1 VALU per gather.
__device__ __forceinline__ void agg_edges(int e0, int e1,
    const int2* __restrict__ csr, const char* __restrict__ Vb, int loff,
    float& ax, float& ay){
  int nq = (e1 - e0) >> 2;
  if (nq <= 0) return;
  const int4* c4 = (const int4*)(csr + e0);
  int qlast = nq - 1;
  int4 ca0 = c4[0], cb0 = c4[1];
  int i1 = (1 <= qlast) ? 1 : qlast;
  int4 ca1 = c4[2 * i1], cb1 = c4[2 * i1 + 1];
  unsigned r0 = *(const unsigned*)(Vb + (unsigned)(ca0.x + loff));
  unsigned r1 = *(const unsigned*)(Vb + (unsigned)(ca0.z + loff));
  unsigned r2 = *(const unsigned*)(Vb + (unsigned)(cb0.x + loff));
  unsigned r3 = *(const unsigned*)(Vb + (unsigned)(cb0.z + loff));
  for (int q = 0; q < nq; ++q){
    unsigned s0 = *(const unsigned*)(Vb + (unsigned)(ca1.x + loff));
    unsigned s1 = *(const unsigned*)(Vb + (unsigned)(ca1.z + loff));
    unsigned s2 = *(const unsigned*)(Vb + (unsigned)(cb1.x + loff));
    unsigned s3 = *(const unsigned*)(Vb + (unsigned)(cb1.z + loff));
    int i2 = (q + 2 <= qlast) ? q + 2 : qlast;
    int4 na = c4[2 * i2], nb = c4[2 * i2 + 1];
    fmix2(ax, ay, __int_as_float(ca0.y), r0);
    fmix2(ax, ay, __int_as_float(ca0.w), r1);
    fmix2(ax, ay, __int_as_float(cb0.y), r2);
    fmix2(ax, ay, __int_as_float(cb0.w), r3);
    ca0 = ca1; cb0 = cb1; ca1 = na; cb1 = nb;
    r0 = s0; r1 = s1; r2 = s2; r3 = s3;
  }
}

// ---- agg layer 1: t1 = A*hw (fp16 rows, fp32 accum) ------------------------
__global__ __launch_bounds__(256) void k_agg1(const int* __restrict__ off,
    const int2* __restrict__ csr, const float* __restrict__ dinv,
    const unsigned int* __restrict__ V, unsigned int* __restrict__ T){
  int grp, chunk; map_block(blockIdx.x, grp, chunk);
  int tid = threadIdx.x;
  int l = tid & 63;
  int wv = __builtin_amdgcn_readfirstlane(tid) >> 6;   // wave-uniform
  const char* Vb = (const char*)(V + (size_t)grp * (NN * 64));
  unsigned int* Tg = T + (size_t)grp * (NN * 64);
  int loff = l * 4;
  for (int it = 0; it < 4; ++it){
    int n = chunk * 16 + wv * 4 + it;
    float din = dinv[n];
    int e0 = off[n], e1 = off[n + 1];
    unsigned sv = *(const unsigned*)(Vb + (unsigned)((n << 8) + loff));
    float ax = 0.f, ay = 0.f;
    fmix2(ax, ay, din, sv);
    agg_edges(e0, e1, csr, Vb, loff, ax, ay);
    Tg[((size_t)n << 6) + l] =
        (unsigned)f2h(din * ax) | ((unsigned)f2h(din * ay) << 16);
  }
}

// ---- agg layer 2 + epilogue: out = tanh(A*t1 + srow*bb + b2) fp32 ----------
__global__ __launch_bounds__(256) void k_agg2(const int* __restrict__ off,
    const int2* __restrict__ csr, const float* __restrict__ dinv,
    const float* __restrict__ srow, const float* __restrict__ bb,
    const float* __restrict__ b2, const unsigned int* __restrict__ V,
    float* __restrict__ out){
  int grp, chunk; map_block(blockIdx.x, grp, chunk);
  int tid = threadIdx.x;
  int l = tid & 63;
  int wv = __builtin_amdgcn_readfirstlane(tid) >> 6;
  int p = l >> 4, fi = l & 15;
  const char* Vb = (const char*)(V + (size_t)grp * (NN * 64));
  int pg = grp * PG + p;
  float2 bbq = ((const float2*)bb)[fi];
  float2 b2q = ((const float2*)b2)[fi];
  float* outp = out + (size_t)pg * (NN * FF);
  int loff = l * 4;
  for (int it = 0; it < 4; ++it){
    int n = chunk * 16 + wv * 4 + it;
    float din = dinv[n];
    int e0 = off[n], e1 = off[n + 1];
    unsigned sv = *(const unsigned*)(Vb + (unsigned)((n << 8) + loff));
    float ax = 0.f, ay = 0.f;
    fmix2(ax, ay, din, sv);
    agg_edges(e0, e1, csr, Vb, loff, ax, ay);
    float sr = srow[n];
    float2 o;
    o.x = tanhf(din * ax + sr * bbq.x + b2q.x);
    o.y = tanhf(din * ay + sr * bbq.y + b2q.y);
    ((float2*)(outp + (size_t)n * FF))[fi] = o;
  }
}

extern "C" void kernel_launch(void* const* d_in, const int* in_sizes, int n_in,
                              void* d_out, int out_size, void* d_ws, size_t ws_size,
                              hipStream_t stream){
  const float* x    = (const float*)d_in[0];
  const float* mask = (const float*)d_in[1];
  const int*   ei   = (const int*)d_in[2];
  const float* W1   = (const float*)d_in[3];
  const float* b1   = (const float*)d_in[4];
  const float* W2   = (const float*)d_in[5];
  const float* b2   = (const float*)d_in[6];
  float* out = (float*)d_out;
  const int E = in_sizes[2] / 2;   // 320000
  const int CSRCAP = E + 3 * NN + 64;  // padded-to-4 worst case + overread slack

  char* wsp = (char*)d_ws;
  auto alloc = [&](size_t bytes) -> char* {
    char* p = wsp; wsp += (bytes + 255) & ~(size_t)255; return p;
  };
  int*   cnt  = (int*)  alloc((size_t)NN * 4);
  int*   off  = (int*)  alloc((size_t)(NN + 1) * 4);
  int*   cur  = (int*)  alloc((size_t)NN * 4);
  float* dinv = (float*)alloc((size_t)NN * 4);
  float* srow = (float*)alloc((size_t)NN * 4);
  float* W12  = (float*)alloc(33 * 32 * 4);
  float* bbv  = (float*)alloc(32 * 4);
  int2*  csr  = (int2*) alloc((size_t)CSRCAP * 8);
  const size_t per_group = (size_t)NN * 64 * 4;    // [n][4p][32f] fp16 = 2.56MB
  unsigned int* hw = (unsigned int*)alloc((size_t)NGRP * per_group);
  unsigned int* t1 = (unsigned int*)alloc((size_t)NGRP * per_group);

  hipMemsetAsync(cnt, 0, (size_t)NN * 4, stream);
  hipMemsetAsync(cur, 0, (size_t)NN * 4, stream);
  hipMemsetAsync(csr, 0, (size_t)CSRCAP * 8, stream);   // pad entries: row 0, w=0
  k_count  <<<(E + 255) / 256, 256, 0, stream>>>(ei + E, cnt, E);
  k_scan   <<<1, 1024, 0, stream>>>(cnt, off, dinv, W1, W2, b1, W12, bbv);
  k_scatter<<<(E + 255) / 256, 256, 0, stream>>>(ei, off, cur, dinv, csr, E);
  k_srow   <<<(NN + 255) / 256, 256, 0, stream>>>(off, csr, dinv, srow);

  k_gemm1<<<dim3(40, 96), 256, 0, stream>>>(x, mask, W12, hw);
  k_agg1 <<<15000, 256, 0, stream>>>(off, csr, dinv, hw, t1);
  k_agg2 <<<15000, 256, 0, stream>>>(off, csr, dinv, srow, bbv, b2, t1, out);
}